// Round 4
// baseline (477.911 us; speedup 1.0000x reference)
//
#include <hip/hip_runtime.h>
#include <stdint.h>

// ---------------------------------------------------------------------------
// NeuralEmbeddingLayer: patchify -> GEMM1(+bias,gelu,x32) -> GEMM2(+bias,+pos)
// R5b = R5 resubmitted verbatim (round-3 failure was container acquisition,
// not a kernel verdict — no passed/absmax/rocprof in the result).
//  - 8 waves (2Mx4N), per-wave 128x64 output (acc[8][4]), BK=64, 256x256 tile
//  - LDS 128 KiB: double-buffered 32KB A-tile + 32KB B-tile
//  - per K-tile: stage(t+1 -> buf^1) issued FIRST (8 gl_lds/thread), counted
//    VMCNT(8) (waits only tile t's loads, issued one iteration earlier),
//    raw barrier, compute (2 kk-slices x 32 MFMA), barrier.
//  - XOR-swizzle granule formulas / fragment addressing / bijective XCD
//    swizzle identical to verified R3/R4 data path.
// ---------------------------------------------------------------------------

typedef __attribute__((ext_vector_type(8))) short bf16x8;   // 8 bf16 = 4 VGPRs
typedef __attribute__((ext_vector_type(4))) float f32x4;    // MFMA C/D frag

#define VMCNT(n) asm volatile("s_waitcnt vmcnt(" #n ")" ::: "memory")
#define CFENCE() asm volatile("" ::: "memory")

__device__ __forceinline__ unsigned short f2bf(float f) {
  union { float f; unsigned u; } v; v.f = f;
  const unsigned u = v.u;
  return (unsigned short)((u + 0x7fffu + ((u >> 16) & 1u)) >> 16);  // RNE
}

__device__ __forceinline__ float gelu_exact(float x) {
  return 0.5f * x * (1.0f + erff(x * 0.70710678118654752440f));
}

// async global->LDS, 16B per lane. HW writes lds_base(lane0) + lane*16.
__device__ __forceinline__ void gl_lds16(const unsigned short* g, unsigned short* l) {
  __builtin_amdgcn_global_load_lds(
      (const __attribute__((address_space(1))) unsigned int*)g,
      (__attribute__((address_space(3))) unsigned int*)l, 16, 0, 0);
}

// --------------------------- prep kernels ----------------------------------

__global__ void cast_f32_bf16(const float* __restrict__ src,
                              unsigned short* __restrict__ dst, int n) {
  const int i = blockIdx.x * 256 + threadIdx.x;
  if (i < n) dst[i] = f2bf(src[i]);
}

// spikes [32][512][1024] f32 -> patches bf16 [32768][512]
__global__ void patchify(const float* __restrict__ spikes,
                         unsigned short* __restrict__ P) {
  const int idx = blockIdx.x * 256 + threadIdx.x;
  const int m = idx >> 7;
  const int c = (idx & 127) << 2;
  const int b = m >> 10, p = m & 1023;
  const int pt = p >> 5, ps = p & 31;
  const int ft = c >> 5, fs = c & 31;
  const float4 v = *(const float4*)(spikes +
      (size_t)(((b << 9) + pt * 16 + ft) << 10) + ps * 32 + fs);
  ushort4 o;
  o.x = f2bf(v.x); o.y = f2bf(v.y); o.z = f2bf(v.z); o.w = f2bf(v.w);
  *(ushort4*)(P + (size_t)m * 512 + c) = o;
}

// G rows b*1025 = gelu(cls)*32 (cls skips b_embed); zero pad rows [32800,32896)
__global__ void g0_and_pad(const float* __restrict__ cls,
                           unsigned short* __restrict__ G) {
  const int i = blockIdx.x * 256 + threadIdx.x;  // 98304 threads
  G[(size_t)32800 * 1024 + i] = 0;
  if (i < 1024) {
    const unsigned short bv = f2bf(gelu_exact(cls[i]) * 32.0f);
    for (int b = 0; b < 32; ++b) G[(size_t)(b * 1025) * 1024 + i] = bv;
  }
}

__global__ void mask_stamp(float* __restrict__ out) {
  const int i = blockIdx.x * 256 + threadIdx.x;
  if (i < 32800) {
    out[33587200 + i] = 1.0f;
    out[33587200 + 32800 + i] = (float)(i % 1025);
  }
}

// --------------------------- staging ---------------------------------------
// LDS region per matrix per buffer: 256 rows x 64 k. Granule g in [0,2048):
// r = g>>3, slot = g&7; granule holds global k-chunk slot^(r&7). Per tile:
// 4 loads/thread/matrix (512 threads x 16B x 4 = 32KB). g = l*512 + tid is
// lane-linear within each wave (gl_lds requirement).
__device__ __forceinline__ void stage_tile256(
    const unsigned short* __restrict__ A, const unsigned short* __restrict__ B,
    int K, int rowStart, int colStart, int rmax, int k0, int tid,
    unsigned short* la, unsigned short* lb) {
#pragma unroll
  for (int l = 0; l < 4; ++l) {
    const int g = l * 512 + tid;
    const int r = g >> 3;
    const int slot = g & 7;
    const int kc = (slot ^ (r & 7)) << 3;
    int ra = rowStart + r;
    if (ra > rmax) ra = rmax;   // GEMM2 tail row-block: clamp into zeroed rows
    gl_lds16(A + (size_t)ra * K + (k0 + kc), la + g * 8);
    gl_lds16(B + (size_t)(colStart + r) * K + (k0 + kc), lb + g * 8);
  }
}

// --------------------------- NT GEMM core ----------------------------------
// C[M,N] = A[M,K]*B[N,K]^T. 256x256 tile, BK=64, 8 waves x (8x4) 16x16x32 mfma.
template <int K, bool GELU_EPI>
__global__ __launch_bounds__(512, 2) void gemm_bt(
    const unsigned short* __restrict__ A, const unsigned short* __restrict__ B,
    const float* __restrict__ bias, unsigned short* __restrict__ Cg,
    float* __restrict__ Cf, const float* __restrict__ pos,
    int Mvalid, int rmax, int nRowBlk) {
  __shared__ __align__(16) unsigned short lsA[2][16384];   // 2 x 32 KB
  __shared__ __align__(16) unsigned short lsB[2][16384];   // 2 x 32 KB
  constexpr int NT = K / 64;

  const int tid = threadIdx.x;
  const int lane = tid & 63;
  const int w = tid >> 6;
  const int quad = lane >> 4;
  const int l16 = lane & 15;
  const int wm = (w >> 2) * 128;   // 2 wave-rows
  const int wn = (w & 3) * 64;     // 4 wave-cols

  // bijective XCD swizzle (m204); row-major so the 4 col-blocks sharing an
  // A-band are contiguous within one XCD's chunk.
  const int nwg = nRowBlk * 4;
  const int q = nwg >> 3, rr = nwg & 7;
  const int xcd = blockIdx.x & 7, jj = blockIdx.x >> 3;
  const int wgid =
      (xcd < rr ? xcd * (q + 1) : rr * (q + 1) + (xcd - rr) * q) + jj;
  const int rowStart = (wgid >> 2) << 8;
  const int colStart = (wgid & 3) << 8;

  f32x4 acc[8][4];
  const f32x4 z = {0.f, 0.f, 0.f, 0.f};
#pragma unroll
  for (int i = 0; i < 8; ++i)
#pragma unroll
    for (int j = 0; j < 4; ++j) acc[i][j] = z;

  // prologue: tile 0 -> buffer 0 (8 loads/thread in flight, no wait)
  stage_tile256(A, B, K, rowStart, colStart, rmax, 0, tid, lsA[0], lsB[0]);

  // fragment read bases (elems). slot = k_chunk ^ (r&7); r&7 == l16&7.
  const int aoff = (wm + l16) << 6;
  const int boff = (wn + l16) << 6;
  const int sl0 = (quad ^ (l16 & 7)) << 3;         // kk=0 : chunk = quad
  const int sl1 = ((4 + quad) ^ (l16 & 7)) << 3;   // kk=32: chunk = 4+quad

  for (int t = 0; t < NT; ++t) {
    const int cur = t & 1;
    if (t + 1 < NT) {
      // issue next tile's 8 loads EARLY, then wait only for tile t's 8
      // (issued one full iteration ago -> latency hidden under compute)
      stage_tile256(A, B, K, rowStart, colStart, rmax, (t + 1) * 64, tid,
                    lsA[cur ^ 1], lsB[cur ^ 1]);
      VMCNT(8);
    } else {
      VMCNT(0);
    }
    __builtin_amdgcn_s_barrier();
    CFENCE();

    const unsigned short* cA = lsA[cur];
    const unsigned short* cB = lsB[cur];

    // kk-slice 0
    {
      bf16x8 af[8], bf[4];
#pragma unroll
      for (int i = 0; i < 8; ++i)
        af[i] = *(const bf16x8*)(cA + aoff + i * 1024 + sl0);
#pragma unroll
      for (int j = 0; j < 4; ++j)
        bf[j] = *(const bf16x8*)(cB + boff + j * 1024 + sl0);
#pragma unroll
      for (int i = 0; i < 8; ++i)
#pragma unroll
        for (int j = 0; j < 4; ++j)
          acc[i][j] = __builtin_amdgcn_mfma_f32_16x16x32_bf16(af[i], bf[j],
                                                              acc[i][j], 0, 0, 0);
    }
    // kk-slice 1
    {
      bf16x8 af[8], bf[4];
#pragma unroll
      for (int i = 0; i < 8; ++i)
        af[i] = *(const bf16x8*)(cA + aoff + i * 1024 + sl1);
#pragma unroll
      for (int j = 0; j < 4; ++j)
        bf[j] = *(const bf16x8*)(cB + boff + j * 1024 + sl1);
#pragma unroll
      for (int i = 0; i < 8; ++i)
#pragma unroll
        for (int j = 0; j < 4; ++j)
          acc[i][j] = __builtin_amdgcn_mfma_f32_16x16x32_bf16(af[i], bf[j],
                                                              acc[i][j], 0, 0, 0);
    }

    CFENCE();
    __builtin_amdgcn_s_barrier();   // all reads of buf[cur] done before next
    CFENCE();                       // iteration's staging overwrites it
  }

  // ---------------------------- epilogue ------------------------------------
#pragma unroll
  for (int i = 0; i < 8; ++i) {
    const int rb = rowStart + wm + i * 16 + quad * 4;
#pragma unroll
    for (int j = 0; j < 4; ++j) {
      const int gc = colStart + wn + j * 16 + l16;
      const float bv = bias[gc];
#pragma unroll
      for (int r = 0; r < 4; ++r) {
        const int row = rb + r;
        float v = acc[i][j][r] + bv;
        if (GELU_EPI) {
          v = gelu_exact(v) * 32.0f;
          const int grow = row + (row >> 10) + 1;   // b*1024+p -> b*1025+p+1
          Cg[(size_t)grow * 1024 + gc] = f2bf(v);
        } else {
          if (row < Mvalid) {
            const int p = row % 1025;               // magic-mul, cheap
            Cf[(size_t)row * 1024 + gc] = v + pos[(size_t)p * 1024 + gc];
          }
        }
      }
    }
  }
}

// --------------------------- launcher --------------------------------------

extern "C" void kernel_launch(void* const* d_in, const int* in_sizes, int n_in,
                              void* d_out, int out_size, void* d_ws, size_t ws_size,
                              hipStream_t stream) {
  const float* spikes  = (const float*)d_in[0];
  const float* W_embed = (const float*)d_in[1];
  const float* b_embed = (const float*)d_in[2];
  const float* cls     = (const float*)d_in[3];
  const float* W_proj  = (const float*)d_in[4];
  const float* b_proj  = (const float*)d_in[5];
  const float* pos     = (const float*)d_in[6];
  float* out = (float*)d_out;

  char* ws = (char*)d_ws;
  unsigned short* P  = (unsigned short*)(ws);              // 32 MiB
  unsigned short* G  = (unsigned short*)(ws + 33554432);   // 64.25 MiB
  unsigned short* WE = (unsigned short*)(ws + 100925440);  // 1 MiB
  unsigned short* WP = (unsigned short*)(ws + 101974016);  // 2 MiB

  hipLaunchKernelGGL(cast_f32_bf16, dim3(2048), dim3(256), 0, stream, W_embed, WE, 524288);
  hipLaunchKernelGGL(cast_f32_bf16, dim3(4096), dim3(256), 0, stream, W_proj, WP, 1048576);
  hipLaunchKernelGGL(patchify, dim3(16384), dim3(256), 0, stream, spikes, P);
  hipLaunchKernelGGL(g0_and_pad, dim3(384), dim3(256), 0, stream, cls, G);
  hipLaunchKernelGGL(mask_stamp, dim3(129), dim3(256), 0, stream, out);

  // GEMM1: [32768,512] x [1024,512]^T -> gelu*32 -> G (bf16). 128x4 = 512 blocks.
  hipLaunchKernelGGL((gemm_bt<512, true>), dim3(512), dim3(512), 0, stream,
                     P, WE, b_embed, G, (float*)nullptr, (const float*)nullptr,
                     0, 32767, 128);
  // GEMM2: [32896,1024] x [1024,1024]^T -> +b_proj +pos -> out (f32).
  // 129x4 = 516 blocks; tail row-block clamps A reads into zeroed rows.
  hipLaunchKernelGGL((gemm_bt<1024, false>), dim3(516), dim3(512), 0, stream,
                     G, WP, b_proj, (unsigned short*)nullptr, out, pos,
                     32800, 32895, 129);
}